// Round 1
// baseline (746.584 us; speedup 1.0000x reference)
//
#include <hip/hip_runtime.h>
#include <math.h>

// SuperpositionNeuron: out[r] = collapse(sigmoid(x@W+b) @ M^T) per row.
// Memory-bound: x is 512 MB of the ~540 MB total traffic.
// Layout: 32 lanes cooperate per row (1 float4/lane = 128 floats), so a
// 64-lane wave reads 1 KiB fully contiguous (rows r, r+1 back to back).
__global__ __launch_bounds__(256) void superpos_kernel(
    const float4* __restrict__ x4,    // [B*32] (x as float4)
    const float4* __restrict__ W4,    // [128]  (W[k][0..3] per float4, row-major [D,S])
    const float*  __restrict__ bvec,  // [4]
    const float*  __restrict__ M,     // [16] row-major [S,S]
    const float*  __restrict__ thrp,  // [1]
    const float*  __restrict__ noise, // [B]
    const float*  __restrict__ u,     // [B]
    const float4* __restrict__ gum4,  // [B]  (gumbel rows as float4)
    float*        __restrict__ out,   // [B]
    int B)
{
    const int lane = threadIdx.x & 31;
    const int row  = blockIdx.x * 8 + (threadIdx.x >> 5);
    if (row >= B) return;

    // Coalesced x load: lane l covers columns [4l, 4l+4)
    const float4 xv = x4[row * 32 + lane];

    // W rows k = 4l .. 4l+3 (tiny, L1/L2-resident)
    const float4 w0 = W4[lane * 4 + 0];
    const float4 w1 = W4[lane * 4 + 1];
    const float4 w2 = W4[lane * 4 + 2];
    const float4 w3 = W4[lane * 4 + 3];

    float d0 = xv.x * w0.x + xv.y * w1.x + xv.z * w2.x + xv.w * w3.x;
    float d1 = xv.x * w0.y + xv.y * w1.y + xv.z * w2.y + xv.w * w3.y;
    float d2 = xv.x * w0.z + xv.y * w1.z + xv.z * w2.z + xv.w * w3.z;
    float d3 = xv.x * w0.w + xv.y * w1.w + xv.z * w2.w + xv.w * w3.w;

    // Butterfly reduction across the 32 lanes of this row's group
    #pragma unroll
    for (int off = 16; off >= 1; off >>= 1) {
        d0 += __shfl_xor(d0, off, 32);
        d1 += __shfl_xor(d1, off, 32);
        d2 += __shfl_xor(d2, off, 32);
        d3 += __shfl_xor(d3, off, 32);
    }

    if (lane == 0) {
        // per-state sigmoid(Linear)
        const float st0 = 1.0f / (1.0f + expf(-(d0 + bvec[0])));
        const float st1 = 1.0f / (1.0f + expf(-(d1 + bvec[1])));
        const float st2 = 1.0f / (1.0f + expf(-(d2 + bvec[2])));
        const float st3 = 1.0f / (1.0f + expf(-(d3 + bvec[3])));

        // interfered[i] = sum_j st[j] * M[i][j]   (state @ M^T)
        const float i0 = st0*M[ 0] + st1*M[ 1] + st2*M[ 2] + st3*M[ 3];
        const float i1 = st0*M[ 4] + st1*M[ 5] + st2*M[ 6] + st3*M[ 7];
        const float i2 = st0*M[ 8] + st1*M[ 9] + st2*M[10] + st3*M[11];
        const float i3 = st0*M[12] + st1*M[13] + st2*M[14] + st3*M[15];

        // bernoulli collapse decision
        const float prob   = 1.0f / (1.0f + expf(-(noise[row] + thrp[0])));
        const bool  should = u[row] < prob;

        // multinomial via gumbel argmax (first-max tie-break, like jnp.argmax)
        const float4 g = gum4[row];
        float best = i0 + g.x; int ch = 0;
        float v;
        v = i1 + g.y; if (v > best) { best = v; ch = 1; }
        v = i2 + g.z; if (v > best) { best = v; ch = 2; }
        v = i3 + g.w; if (v > best) { best = v; ch = 3; }
        const float meas = (ch == 0) ? i0 : (ch == 1) ? i1 : (ch == 2) ? i2 : i3;

        const float mean = 0.25f * (i0 + i1 + i2 + i3);
        out[row] = should ? meas : mean;
    }
}

extern "C" void kernel_launch(void* const* d_in, const int* in_sizes, int n_in,
                              void* d_out, int out_size, void* d_ws, size_t ws_size,
                              hipStream_t stream) {
    const float4* x4    = (const float4*)d_in[0];
    const float4* W4    = (const float4*)d_in[1];
    const float*  bvec  = (const float*)d_in[2];
    const float*  M     = (const float*)d_in[3];
    const float*  thrp  = (const float*)d_in[4];
    const float*  noise = (const float*)d_in[5];
    const float*  u     = (const float*)d_in[6];
    const float4* gum4  = (const float4*)d_in[7];
    float*        out   = (float*)d_out;

    const int B = out_size;              // [B,1] output
    const int grid = (B + 7) / 8;        // 8 rows per 256-thread block
    superpos_kernel<<<grid, 256, 0, stream>>>(x4, W4, bvec, M, thrp, noise, u,
                                              gum4, out, B);
}

// Round 2
// 719.285 us; speedup vs baseline: 1.0380x; 1.0380x over previous
//
#include <hip/hip_runtime.h>
#include <math.h>

// SuperpositionNeuron: out[r] = collapse(sigmoid(x@W+b) @ M^T) per row.
// Memory-bound: x is 512 MB of ~540 MB total traffic -> floor ~85 us @ 6.3 TB/s.
//
// Layout: 8 lanes per row, 8 rows per wave, 32 rows per 256-thread block.
// Each load instruction j: lane (r,s) reads float4 at row r, chunk s+8j ->
// the wave fetches 8 rows x 128 B contiguous = 1 KiB fully dense.
// Reduction: 3 shfl_xor levels within 8-lane groups (vs 5 levels at 32 l/row);
// epilogue computed on ALL lanes (same-address loads broadcast-coalesce),
// only the final store is predicated on s==0 -> no exec-mask branches.
__global__ __launch_bounds__(256) void superpos_kernel(
    const float4* __restrict__ x4,    // [B*32] (x as float4)
    const float4* __restrict__ W4,    // [128]  (W[k][0..3] per float4, row-major [D,S])
    const float*  __restrict__ bvec,  // [4]
    const float*  __restrict__ M,     // [16] row-major [S,S]
    const float*  __restrict__ thrp,  // [1]
    const float*  __restrict__ noise, // [B]
    const float*  __restrict__ u,     // [B]
    const float4* __restrict__ gum4,  // [B]  (gumbel rows as float4)
    float*        __restrict__ out,   // [B]
    int B)
{
    const int tid = threadIdx.x;
    const int s   = tid & 7;                      // sub-lane within row group
    const int row = blockIdx.x * 32 + (tid >> 3); // 32 rows per block
    if (row >= B) return;

    const float4* __restrict__ xrow = x4 + (size_t)row * 32;

    float d0 = 0.f, d1 = 0.f, d2 = 0.f, d3 = 0.f;
    #pragma unroll
    for (int j = 0; j < 4; ++j) {
        const int c = s + 8 * j;        // float4-column index, 0..31
        const float4 xv = xrow[c];
        const float4 w0 = W4[c * 4 + 0];
        const float4 w1 = W4[c * 4 + 1];
        const float4 w2 = W4[c * 4 + 2];
        const float4 w3 = W4[c * 4 + 3];
        d0 += xv.x * w0.x + xv.y * w1.x + xv.z * w2.x + xv.w * w3.x;
        d1 += xv.x * w0.y + xv.y * w1.y + xv.z * w2.y + xv.w * w3.y;
        d2 += xv.x * w0.z + xv.y * w1.z + xv.z * w2.z + xv.w * w3.z;
        d3 += xv.x * w0.w + xv.y * w1.w + xv.z * w2.w + xv.w * w3.w;
    }

    // Reduce across the 8 lanes of this row group (3 levels)
    #pragma unroll
    for (int off = 4; off >= 1; off >>= 1) {
        d0 += __shfl_xor(d0, off, 8);
        d1 += __shfl_xor(d1, off, 8);
        d2 += __shfl_xor(d2, off, 8);
        d3 += __shfl_xor(d3, off, 8);
    }
    // All 8 lanes now hold the full dot products for this row.

    // per-state sigmoid(Linear)
    const float st0 = 1.0f / (1.0f + expf(-(d0 + bvec[0])));
    const float st1 = 1.0f / (1.0f + expf(-(d1 + bvec[1])));
    const float st2 = 1.0f / (1.0f + expf(-(d2 + bvec[2])));
    const float st3 = 1.0f / (1.0f + expf(-(d3 + bvec[3])));

    // interfered[i] = sum_j st[j] * M[i][j]   (state @ M^T)
    const float i0 = st0*M[ 0] + st1*M[ 1] + st2*M[ 2] + st3*M[ 3];
    const float i1 = st0*M[ 4] + st1*M[ 5] + st2*M[ 6] + st3*M[ 7];
    const float i2 = st0*M[ 8] + st1*M[ 9] + st2*M[10] + st3*M[11];
    const float i3 = st0*M[12] + st1*M[13] + st2*M[14] + st3*M[15];

    // bernoulli collapse decision (same-address loads broadcast across group)
    const float prob   = 1.0f / (1.0f + expf(-(noise[row] + thrp[0])));
    const bool  should = u[row] < prob;

    // multinomial via gumbel argmax (first-max tie-break, like jnp.argmax)
    const float4 g = gum4[row];
    float best = i0 + g.x; int ch = 0;
    float v;
    v = i1 + g.y; if (v > best) { best = v; ch = 1; }
    v = i2 + g.z; if (v > best) { best = v; ch = 2; }
    v = i3 + g.w; if (v > best) { best = v; ch = 3; }
    const float meas = (ch == 0) ? i0 : (ch == 1) ? i1 : (ch == 2) ? i2 : i3;

    const float mean = 0.25f * (i0 + i1 + i2 + i3);
    const float result = should ? meas : mean;

    if (s == 0) out[row] = result;
}

extern "C" void kernel_launch(void* const* d_in, const int* in_sizes, int n_in,
                              void* d_out, int out_size, void* d_ws, size_t ws_size,
                              hipStream_t stream) {
    const float4* x4    = (const float4*)d_in[0];
    const float4* W4    = (const float4*)d_in[1];
    const float*  bvec  = (const float*)d_in[2];
    const float*  M     = (const float*)d_in[3];
    const float*  thrp  = (const float*)d_in[4];
    const float*  noise = (const float*)d_in[5];
    const float*  u     = (const float*)d_in[6];
    const float4* gum4  = (const float4*)d_in[7];
    float*        out   = (float*)d_out;

    const int B = out_size;               // [B,1] output
    const int grid = (B + 31) / 32;       // 32 rows per 256-thread block
    superpos_kernel<<<grid, 256, 0, stream>>>(x4, W4, bvec, M, thrp, noise, u,
                                              gum4, out, B);
}